// Round 7
// baseline (1169.884 us; speedup 1.0000x reference)
//
#include <hip/hip_runtime.h>
#include <hip/hip_fp16.h>
#include <math.h>

#define NNODES  50000
#define NEDGES  1600000
#define NGRAPHS 128
#define HID     128
#define NG      50
#define NITER   3
#define TPTS    2048
#define WMAX    12.0f
#define PI_F    3.14159265358979323846f

typedef __attribute__((ext_vector_type(4))) _Float16 half4;
typedef __attribute__((ext_vector_type(4))) float   f32x4;

__device__ __forceinline__ float ssp(float x) {
    float sp = fmaxf(x, 0.0f) + log1pf(expf(-fabsf(x)));
    return sp - 0.69314718055994530942f;
}

// ---------------- h = emb[z] (fp32 master + fp16 shadow) ----------------
__global__ __launch_bounds__(256) void k_init_h(const float* __restrict__ emb,
                                                const int* __restrict__ z,
                                                float* __restrict__ h,
                                                _Float16* __restrict__ hH)
{
    int idx = blockIdx.x * 256 + threadIdx.x;
    int n = idx >> 7, c = idx & 127;
    float v = emb[(z[n] << 7) + c];
    h[idx] = v;
    hH[idx] = (_Float16)v;
}

// ---------------- weight transpose+cast: out[it][c][j] = in[it][j][c] fp16 ----------------
__global__ __launch_bounds__(128) void k_wt(const float* __restrict__ in,
                                            _Float16* __restrict__ out)
{
    int it = blockIdx.x >> 7, c = blockIdx.x & 127, j = threadIdx.x;
    out[(size_t)it * 16384 + c * 128 + j] = (_Float16)in[(size_t)it * 16384 + j * 128 + c];
}

// ---------------- LUT build, fused delta: ti layout (v0,v1,d0,d1) per lane-pair ----------------
__global__ __launch_bounds__(128) void k_table(const float* __restrict__ W1,
                                               const float* __restrict__ B1,
                                               const float* __restrict__ W2,
                                               const float* __restrict__ B2,
                                               __half* __restrict__ ti)
{
    int it = blockIdx.x / TPTS;
    int pt = blockIdx.x - it * TPTS;
    const float* W1i = W1 + (size_t)it * NG * HID;
    const float* B1i = B1 + (size_t)it * HID;
    const float* W2i = W2 + (size_t)it * HID * HID;
    const float* B2i = B2 + (size_t)it * HID;

    const float step = WMAX / (float)(TPTS - 1);
    float w0 = pt * step;
    int ptn = (pt < TPTS - 1) ? pt + 1 : pt;
    float w1v = ptn * step;

    __shared__ float sEA[2][NG];
    __shared__ float sT1[2][HID];
    int k = threadIdx.x;
    {
        float dx = 8.0f / 49.0f;
        float coeff = -0.5f / (dx * dx);
        if (k < NG) {
            float diff = w0 - (float)k * dx;
            sEA[0][k] = expf(coeff * diff * diff);
        } else if (k >= 64 && k < 64 + NG) {
            float diff = w1v - (float)(k - 64) * dx;
            sEA[1][k - 64] = expf(coeff * diff * diff);
        }
    }
    __syncthreads();
    float a0 = B1i[k], a1 = a0;
    for (int g = 0; g < NG; ++g) {
        float wv = W1i[g * HID + k];
        a0 = fmaf(sEA[0][g], wv, a0);
        a1 = fmaf(sEA[1][g], wv, a1);
    }
    sT1[0][k] = ssp(a0);
    sT1[1][k] = ssp(a1);
    __syncthreads();
    float b0 = B2i[k], b1v = b0;
    for (int j = 0; j < HID; ++j) {
        float wv = W2i[j * HID + k];
        b0  = fmaf(sT1[0][j], wv, b0);
        b1v = fmaf(sT1[1][j], wv, b1v);
    }
    size_t base = ((size_t)it * TPTS + pt) * 256;
    int pair = k >> 1, within = k & 1;
    ti[base + pair * 4 + within]     = __float2half(b0);
    ti[base + pair * 4 + within + 2] = __float2half(b1v - b0);
}

// ---------------- CSR build: histogram of dst ----------------
__global__ __launch_bounds__(256) void k_hist(const int* __restrict__ ei,
                                              int* __restrict__ deg)
{
    int e = blockIdx.x * 256 + threadIdx.x;
    if (e >= NEDGES) return;
    atomicAdd(&deg[ei[NEDGES + e]], 1);
}

// ---------------- CSR build: exclusive scan, chunk-per-thread ----------------
#define SCAN_T 1024
#define CHUNK  49
__global__ __launch_bounds__(SCAN_T) void k_scan(const int* __restrict__ deg,
                                                 int* __restrict__ rowptr,
                                                 int* __restrict__ cursor)
{
    int tid = threadIdx.x;
    int base = tid * CHUNK;
    int vals[CHUNK];
    int local = 0;
    #pragma unroll
    for (int i = 0; i < CHUNK; ++i) {
        int idx = base + i;
        int v = (idx < NNODES) ? deg[idx] : 0;
        vals[i] = local;
        local += v;
    }
    int lane = tid & 63, wid = tid >> 6;
    int x = local;
    #pragma unroll
    for (int off = 1; off < 64; off <<= 1) {
        int y = __shfl_up(x, off);
        if (lane >= off) x += y;
    }
    __shared__ int wsum[16];
    __shared__ int woff[17];
    if (lane == 63) wsum[wid] = x;
    __syncthreads();
    if (tid == 0) {
        int acc = 0;
        #pragma unroll
        for (int i = 0; i < 16; ++i) { woff[i] = acc; acc += wsum[i]; }
        woff[16] = acc;
    }
    __syncthreads();
    int threadExcl = woff[wid] + x - local;
    #pragma unroll
    for (int i = 0; i < CHUNK; ++i) {
        int idx = base + i;
        if (idx < NNODES) {
            int p = threadExcl + vals[i];
            rowptr[idx] = p;
            cursor[idx] = p;
        }
    }
    if (tid == SCAN_T - 1) rowptr[NNODES] = woff[16];
}

// ---------------- CSR build: scatter rich edge records, sorted by dst ----------------
// record: (src byte-off into hf row, table byte-off, fr as half2, C as half2)
__global__ __launch_bounds__(256) void k_scatter(const int* __restrict__ ei,
                                                 const float* __restrict__ pos,
                                                 const float* __restrict__ shift,
                                                 int* __restrict__ cursor,
                                                 uint4* __restrict__ rec)
{
    int e = blockIdx.x * 256 + threadIdx.x;
    if (e >= NEDGES) return;
    int s = ei[e], d = ei[NEDGES + e];
    float rx = pos[3*s+0] - (pos[3*d+0] + shift[3*e+0]);
    float ry = pos[3*s+1] - (pos[3*d+1] + shift[3*e+1]);
    float rz = pos[3*s+2] - (pos[3*d+2] + shift[3*e+2]);
    float w = sqrtf(rx*rx + ry*ry + rz*rz);
    const float SCALE = (float)(TPTS - 1) / WMAX;
    float t = fminf(w * SCALE, (float)(TPTS - 1));
    int i0 = (int)t; if (i0 > TPTS - 2) i0 = TPTS - 2;
    float fr = t - (float)i0;
    float C = 0.5f * (cosf(w * (PI_F / 8.0f)) + 1.0f);
    __half2 fr2 = __float2half2_rn(fr);
    __half2 c2  = __float2half2_rn(C);
    int slot = atomicAdd(&cursor[d], 1);
    rec[slot] = make_uint4((unsigned)(s * 256), (unsigned)(i0 * 512),
                           *(unsigned*)&fr2, *(unsigned*)&c2);
}

// ---------------- gather: packed fp16 math, scalar-base addressing ----------------
__device__ __forceinline__ void edge_contrib(uint4 rv,
                                             const char* __restrict__ hfLane,
                                             const char* __restrict__ tbLane,
                                             float& ax, float& ay)
{
    int srcB = __builtin_amdgcn_readfirstlane((int)rv.x);
    int tblO = __builtin_amdgcn_readfirstlane((int)rv.y);
    int fru  = __builtin_amdgcn_readfirstlane((int)rv.z);
    int cu   = __builtin_amdgcn_readfirstlane((int)rv.w);
    __half2 fr2 = *reinterpret_cast<__half2*>(&fru);
    __half2 c2  = *reinterpret_cast<__half2*>(&cu);
    uint2 tv = *reinterpret_cast<const uint2*>(tbLane + tblO);
    __half2 hv = *reinterpret_cast<const __half2*>(hfLane + srcB);
    __half2 vals = *reinterpret_cast<__half2*>(&tv.x);
    __half2 dels = *reinterpret_cast<__half2*>(&tv.y);
    __half2 f2 = __hfma2(fr2, dels, vals);   // lerp, v_pk_fma_f16
    __half2 ch = __hmul2(c2, hv);            // cutoff*hf, v_pk_mul_f16
    ax = fmaf(__low2float(f2),  __low2float(ch),  ax);   // v_fma_mix_f32
    ay = fmaf(__high2float(f2), __high2float(ch), ay);
}

__global__ __launch_bounds__(256) void k_gather(const uint4* __restrict__ rec,
                                                const int* __restrict__ rowptr,
                                                const __half* __restrict__ hfH,
                                                const __half* __restrict__ tableH,
                                                __half2* __restrict__ aggH)
{
    int node = blockIdx.x * 4 + (threadIdx.x >> 6);
    int lane = threadIdx.x & 63;
    const char* hfLane = (const char*)hfH + lane * 4;
    const char* tbLane = (const char*)tableH + lane * 8;
    int beg = rowptr[node], end = rowptr[node + 1];
    float ax0 = 0.f, ay0 = 0.f, ax1 = 0.f, ay1 = 0.f;
    int k = beg;
    for (; k + 4 <= end; k += 4) {
        uint4 r0 = rec[k], r1 = rec[k+1], r2 = rec[k+2], r3 = rec[k+3];
        edge_contrib(r0, hfLane, tbLane, ax0, ay0);
        edge_contrib(r1, hfLane, tbLane, ax1, ay1);
        edge_contrib(r2, hfLane, tbLane, ax0, ay0);
        edge_contrib(r3, hfLane, tbLane, ax1, ay1);
    }
    for (; k < end; ++k) edge_contrib(rec[k], hfLane, tbLane, ax0, ay0);
    aggH[(size_t)node * 64 + lane] = __floats2half2_rn(ax0 + ax1, ay0 + ay1);
}

// ---------------- MFMA GEMM: outH = hH @ Wt^T (initial hf only) ----------------
__global__ __launch_bounds__(256) void k_ngemm_mfma(const _Float16* __restrict__ hH,
                                                    const _Float16* __restrict__ Wt,
                                                    _Float16* __restrict__ outH)
{
    int tid = threadIdx.x;
    int wave = tid >> 6, l = tid & 63;
    int lr = l & 15, lg = l >> 4;
    int r0 = blockIdx.x * 64 + wave * 16;
    f32x4 acc[8];
    #pragma unroll
    for (int ct = 0; ct < 8; ++ct) acc[ct] = (f32x4){0.f, 0.f, 0.f, 0.f};
    const _Float16* aRow = hH + (size_t)(r0 + lr) * HID;
    #pragma unroll
    for (int kk = 0; kk < 8; ++kk) {
        half4 a = *(const half4*)(aRow + kk * 16 + lg * 4);
        #pragma unroll
        for (int ct = 0; ct < 8; ++ct) {
            half4 b = *(const half4*)(Wt + (size_t)(ct * 16 + lr) * HID + kk * 16 + lg * 4);
            acc[ct] = __builtin_amdgcn_mfma_f32_16x16x16f16(a, b, acc[ct], 0, 0, 0);
        }
    }
    #pragma unroll
    for (int ct = 0; ct < 8; ++ct) {
        #pragma unroll
        for (int r = 0; r < 4; ++r) {
            int row = r0 + lg * 4 + r;
            if (row < NNODES) outH[(size_t)row * HID + ct * 16 + lr] = (_Float16)acc[ct][r];
        }
    }
}

// ---------------- MFMA fused update: h += ssp(aggH@W2t+b2)@Lt+lb ; hf_next = h_new@W1n ----------------
__global__ __launch_bounds__(256) void k_update_mfma(const _Float16* __restrict__ aggH,
                                                     const _Float16* __restrict__ W2t,
                                                     const float* __restrict__ B2,
                                                     const _Float16* __restrict__ Lt,
                                                     const float* __restrict__ LB,
                                                     float* __restrict__ h,
                                                     _Float16* __restrict__ hH,
                                                     const _Float16* __restrict__ W1n,
                                                     _Float16* __restrict__ hfOut)
{
    __shared__ _Float16 sT[64 * 128];     // 16 KB, XOR-swizzled, wave-private rows
    int tid = threadIdx.x;
    int wave = tid >> 6, l = tid & 63;
    int lr = l & 15, lg = l >> 4;
    int r0 = blockIdx.x * 64 + wave * 16;

    f32x4 acc[8];
    #pragma unroll
    for (int ct = 0; ct < 8; ++ct) acc[ct] = (f32x4){0.f, 0.f, 0.f, 0.f};
    const _Float16* aRow = aggH + (size_t)(r0 + lr) * HID;
    #pragma unroll
    for (int kk = 0; kk < 8; ++kk) {
        half4 a = *(const half4*)(aRow + kk * 16 + lg * 4);
        #pragma unroll
        for (int ct = 0; ct < 8; ++ct) {
            half4 b = *(const half4*)(W2t + (size_t)(ct * 16 + lr) * HID + kk * 16 + lg * 4);
            acc[ct] = __builtin_amdgcn_mfma_f32_16x16x16f16(a, b, acc[ct], 0, 0, 0);
        }
    }
    // ssp + bias -> swizzled LDS fp16
    #pragma unroll
    for (int ct = 0; ct < 8; ++ct) {
        #pragma unroll
        for (int r = 0; r < 4; ++r) {
            int rl = wave * 16 + lg * 4 + r;
            int col = ct * 16 + lr;
            float v = ssp(acc[ct][r] + B2[col]);
            int byte = rl * 256 + col * 2;
            byte ^= (rl & 7) << 4;
            *(_Float16*)((char*)sT + byte) = (_Float16)v;
        }
    }
    __syncthreads();
    f32x4 acc2[8];
    #pragma unroll
    for (int ct = 0; ct < 8; ++ct) acc2[ct] = (f32x4){0.f, 0.f, 0.f, 0.f};
    int rl2 = wave * 16 + lr;
    #pragma unroll
    for (int kk = 0; kk < 8; ++kk) {
        int byte = rl2 * 256 + (kk * 16 + lg * 4) * 2;
        byte ^= (rl2 & 7) << 4;
        half4 a = *(const half4*)((char*)sT + byte);
        #pragma unroll
        for (int ct = 0; ct < 8; ++ct) {
            half4 b = *(const half4*)(Lt + (size_t)(ct * 16 + lr) * HID + kk * 16 + lg * 4);
            acc2[ct] = __builtin_amdgcn_mfma_f32_16x16x16f16(a, b, acc2[ct], 0, 0, 0);
        }
    }
    __syncthreads();   // phase-2 LDS reads complete before overwrite
    #pragma unroll
    for (int ct = 0; ct < 8; ++ct) {
        #pragma unroll
        for (int r = 0; r < 4; ++r) {
            int row = r0 + lg * 4 + r;
            int col = ct * 16 + lr;
            float hv = 0.f;
            if (row < NNODES) {
                hv = h[(size_t)row * HID + col] + acc2[ct][r] + LB[col];
                h[(size_t)row * HID + col] = hv;
                hH[(size_t)row * HID + col] = (_Float16)hv;
            }
            if (W1n) {
                int rl = wave * 16 + lg * 4 + r;
                int byte = rl * 256 + col * 2;
                byte ^= (rl & 7) << 4;
                *(_Float16*)((char*)sT + byte) = (_Float16)hv;
            }
        }
    }
    if (W1n) {
        __syncthreads();
        f32x4 acc3[8];
        #pragma unroll
        for (int ct = 0; ct < 8; ++ct) acc3[ct] = (f32x4){0.f, 0.f, 0.f, 0.f};
        #pragma unroll
        for (int kk = 0; kk < 8; ++kk) {
            int byte = rl2 * 256 + (kk * 16 + lg * 4) * 2;
            byte ^= (rl2 & 7) << 4;
            half4 a = *(const half4*)((char*)sT + byte);
            #pragma unroll
            for (int ct = 0; ct < 8; ++ct) {
                half4 b = *(const half4*)(W1n + (size_t)(ct * 16 + lr) * HID + kk * 16 + lg * 4);
                acc3[ct] = __builtin_amdgcn_mfma_f32_16x16x16f16(a, b, acc3[ct], 0, 0, 0);
            }
        }
        #pragma unroll
        for (int ct = 0; ct < 8; ++ct) {
            #pragma unroll
            for (int r = 0; r < 4; ++r) {
                int row = r0 + lg * 4 + r;
                if (row < NNODES) hfOut[(size_t)row * HID + ct * 16 + lr] = (_Float16)acc3[ct][r];
            }
        }
    }
}

// ---------------- head: 128-row tile, fused ssp+dot+atomic ----------------
__global__ __launch_bounds__(512) void k_head(const float* __restrict__ h,
                                              const float* __restrict__ w1,
                                              const float* __restrict__ b1,
                                              const float* __restrict__ w2,
                                              const float* __restrict__ b2,
                                              const int* __restrict__ batch,
                                              float* __restrict__ sums_pad)
{
    __shared__ float sA[128 * 132];
    int r0 = blockIdx.x * 128;
    int tid = threadIdx.x;
    for (int idx = tid; idx < 128 * 32; idx += 512) {
        int r = idx >> 5, c4 = idx & 31;
        int row = r0 + r;
        float4 v = make_float4(0.f, 0.f, 0.f, 0.f);
        if (row < NNODES) v = *(const float4*)(h + (size_t)row * HID + c4 * 4);
        *(float4*)(&sA[r * 132 + c4 * 4]) = v;
    }
    __syncthreads();
    int tx = tid & 7, ty = tid >> 3;
    int cc = tx * 8, ee = ty * 2;
    float acc[2][8];
    {
        float4 b0 = *(const float4*)(b1 + cc);
        float4 bb = *(const float4*)(b1 + cc + 4);
        #pragma unroll
        for (int e = 0; e < 2; ++e) {
            acc[e][0]=b0.x; acc[e][1]=b0.y; acc[e][2]=b0.z; acc[e][3]=b0.w;
            acc[e][4]=bb.x; acc[e][5]=bb.y; acc[e][6]=bb.z; acc[e][7]=bb.w;
        }
    }
    #pragma unroll 4
    for (int j = 0; j < HID; ++j) {
        float a0 = sA[(ee + 0) * 132 + j];
        float a1 = sA[(ee + 1) * 132 + j];
        float4 w0 = *(const float4*)(w1 + (size_t)j * 64 + cc);
        float4 wv1 = *(const float4*)(w1 + (size_t)j * 64 + cc + 4);
        float wv[8] = {w0.x,w0.y,w0.z,w0.w,wv1.x,wv1.y,wv1.z,wv1.w};
        #pragma unroll
        for (int c = 0; c < 8; ++c) {
            acc[0][c] = fmaf(a0, wv[c], acc[0][c]);
            acc[1][c] = fmaf(a1, wv[c], acc[1][c]);
        }
    }
    float4 w2a = *(const float4*)(w2 + cc);
    float4 w2b = *(const float4*)(w2 + cc + 4);
    float w2v[8] = {w2a.x,w2a.y,w2a.z,w2a.w,w2b.x,w2b.y,w2b.z,w2b.w};
    float bias2 = b2[0];
    #pragma unroll
    for (int e = 0; e < 2; ++e) {
        float part = 0.f;
        #pragma unroll
        for (int c = 0; c < 8; ++c) part = fmaf(ssp(acc[e][c]), w2v[c], part);
        part += __shfl_down(part, 4, 8);
        part += __shfl_down(part, 2, 8);
        part += __shfl_down(part, 1, 8);
        if (tx == 0) {
            int row = r0 + ee + e;
            if (row < NNODES) {
                int b = batch[row];
                atomicAdd(&sums_pad[b * 16], part + bias2);
            }
        }
    }
}

// ---------------- final: counts via binary search on sorted batch ----------------
__global__ void k_final(const float* __restrict__ sums_pad,
                        const int* __restrict__ batch,
                        float* __restrict__ out)
{
    int g = threadIdx.x;
    if (g >= NGRAPHS) return;
    int lo = 0, hi = NNODES;
    while (lo < hi) { int mid = (lo + hi) >> 1; if (batch[mid] < g) lo = mid + 1; else hi = mid; }
    int a = lo;
    lo = 0; hi = NNODES;
    while (lo < hi) { int mid = (lo + hi) >> 1; if (batch[mid] < g + 1) lo = mid + 1; else hi = mid; }
    float cnt = (float)(lo - a);
    out[g] = sums_pad[g * 16] / fmaxf(cnt, 1.0f);
}

extern "C" void kernel_launch(void* const* d_in, const int* in_sizes, int n_in,
                              void* d_out, int out_size, void* d_ws, size_t ws_size,
                              hipStream_t stream)
{
    const float* pos     = (const float*)d_in[0];
    const float* shift   = (const float*)d_in[1];
    const float* emb     = (const float*)d_in[2];
    const float* mlp_w1  = (const float*)d_in[3];
    const float* mlp_b1  = (const float*)d_in[4];
    const float* mlp_w2  = (const float*)d_in[5];
    const float* mlp_b2  = (const float*)d_in[6];
    const float* cf_w1   = (const float*)d_in[7];
    const float* cf_w2   = (const float*)d_in[8];
    const float* cf_b2   = (const float*)d_in[9];
    const float* lin_w   = (const float*)d_in[10];
    const float* lin_b   = (const float*)d_in[11];
    const float* head_w1 = (const float*)d_in[12];
    const float* head_b1 = (const float*)d_in[13];
    const float* head_w2 = (const float*)d_in[14];
    const float* head_b2 = (const float*)d_in[15];
    const int*   z       = (const int*)d_in[16];
    const int*   ei      = (const int*)d_in[17];
    const int*   batch   = (const int*)d_in[18];
    float* out = (float*)d_out;

    float* ws = (float*)d_ws;
    size_t off = 0;
    float*    h       = ws + off; off += (size_t)NNODES * HID;
    _Float16* hH      = (_Float16*)(ws + off); off += (size_t)(NNODES + 64) * HID / 2;
    _Float16* hfH     = (_Float16*)(ws + off); off += (size_t)(NNODES + 64) * HID / 2;
    _Float16* aggH    = (_Float16*)(ws + off); off += (size_t)(NNODES + 64) * HID / 2;
    __half*   tableH  = (__half*)(ws + off); off += (size_t)3 * TPTS * 256 / 2;
    _Float16* w1t     = (_Float16*)(ws + off); off += (size_t)3 * HID * HID / 2;
    _Float16* w2t     = (_Float16*)(ws + off); off += (size_t)3 * HID * HID / 2;
    _Float16* lwt     = (_Float16*)(ws + off); off += (size_t)3 * HID * HID / 2;
    uint4*    rec     = (uint4*)(ws + off); off += (size_t)4 * NEDGES;
    int*      rowptr  = (int*)(ws + off); off += NNODES + 1;
    int*      deg     = (int*)(ws + off); off += NNODES;
    int*      cursor  = (int*)(ws + off); off += NNODES;
    float*    sums_pad= ws + off; off += NGRAPHS * 16;

    hipMemsetAsync(deg, 0, NNODES * sizeof(int), stream);
    hipMemsetAsync(sums_pad, 0, NGRAPHS * 16 * sizeof(float), stream);

    k_hist<<<(NEDGES + 255) / 256, 256, 0, stream>>>(ei, deg);
    k_scan<<<1, SCAN_T, 0, stream>>>(deg, rowptr, cursor);
    k_scatter<<<(NEDGES + 255) / 256, 256, 0, stream>>>(ei, pos, shift, cursor, rec);

    k_init_h<<<NNODES * HID / 256, 256, 0, stream>>>(emb, z, h, hH);
    k_table<<<3 * TPTS, 128, 0, stream>>>(mlp_w1, mlp_b1, mlp_w2, mlp_b2, tableH);
    k_wt<<<3 * 128, 128, 0, stream>>>(cf_w1, w1t);
    k_wt<<<3 * 128, 128, 0, stream>>>(cf_w2, w2t);
    k_wt<<<3 * 128, 128, 0, stream>>>(lin_w, lwt);

    int gblk = (NNODES + 63) / 64;
    k_ngemm_mfma<<<gblk, 256, 0, stream>>>(hH, w1t, hfH);
    for (int i = 0; i < NITER; ++i) {
        k_gather<<<NNODES / 4, 256, 0, stream>>>(rec, rowptr, (const __half*)hfH,
                                                 tableH + (size_t)i * TPTS * 256,
                                                 (__half2*)aggH);
        k_update_mfma<<<gblk, 256, 0, stream>>>(aggH, w2t + (size_t)i * HID * HID,
                                                cf_b2 + (size_t)i * HID,
                                                lwt + (size_t)i * HID * HID,
                                                lin_b + (size_t)i * HID, h, hH,
                                                (i < NITER - 1) ? w1t + (size_t)(i + 1) * HID * HID : nullptr,
                                                hfH);
    }
    k_head<<<(NNODES + 127) / 128, 512, 0, stream>>>(h, head_w1, head_b1, head_w2, head_b2, batch, sums_pad);
    k_final<<<1, 128, 0, stream>>>(sums_pad, batch, out);
}

// Round 8
// 1100.735 us; speedup vs baseline: 1.0628x; 1.0628x over previous
//
#include <hip/hip_runtime.h>
#include <hip/hip_fp16.h>
#include <math.h>

#define NNODES  50000
#define NEDGES  1600000
#define NGRAPHS 128
#define HID     128
#define NG      50
#define NITER   3
#define TPTS    2048
#define WMAX    12.0f
#define PI_F    3.14159265358979323846f

typedef __attribute__((ext_vector_type(4))) _Float16 half4;
typedef __attribute__((ext_vector_type(4))) float   f32x4;

__device__ __forceinline__ float ssp(float x) {
    float sp = fmaxf(x, 0.0f) + log1pf(expf(-fabsf(x)));
    return sp - 0.69314718055994530942f;
}

// ---------------- h = emb[z] (fp32 master + fp16 shadow) ----------------
__global__ __launch_bounds__(256) void k_init_h(const float* __restrict__ emb,
                                                const int* __restrict__ z,
                                                float* __restrict__ h,
                                                _Float16* __restrict__ hH)
{
    int idx = blockIdx.x * 256 + threadIdx.x;
    int n = idx >> 7, c = idx & 127;
    float v = emb[(z[n] << 7) + c];
    h[idx] = v;
    hH[idx] = (_Float16)v;
}

// ---------------- weight transpose+cast: out[it][c][j] = in[it][j][c] fp16 ----------------
__global__ __launch_bounds__(128) void k_wt(const float* __restrict__ in,
                                            _Float16* __restrict__ out)
{
    int it = blockIdx.x >> 7, c = blockIdx.x & 127, j = threadIdx.x;
    out[(size_t)it * 16384 + c * 128 + j] = (_Float16)in[(size_t)it * 16384 + j * 128 + c];
}

// ---------------- LUT build, fused delta: ti layout (v0,v1,d0,d1) per lane-pair ----------------
__global__ __launch_bounds__(128) void k_table(const float* __restrict__ W1,
                                               const float* __restrict__ B1,
                                               const float* __restrict__ W2,
                                               const float* __restrict__ B2,
                                               __half* __restrict__ ti)
{
    int it = blockIdx.x / TPTS;
    int pt = blockIdx.x - it * TPTS;
    const float* W1i = W1 + (size_t)it * NG * HID;
    const float* B1i = B1 + (size_t)it * HID;
    const float* W2i = W2 + (size_t)it * HID * HID;
    const float* B2i = B2 + (size_t)it * HID;

    const float step = WMAX / (float)(TPTS - 1);
    float w0 = pt * step;
    int ptn = (pt < TPTS - 1) ? pt + 1 : pt;
    float w1v = ptn * step;

    __shared__ float sEA[2][NG];
    __shared__ float sT1[2][HID];
    int k = threadIdx.x;
    {
        float dx = 8.0f / 49.0f;
        float coeff = -0.5f / (dx * dx);
        if (k < NG) {
            float diff = w0 - (float)k * dx;
            sEA[0][k] = expf(coeff * diff * diff);
        } else if (k >= 64 && k < 64 + NG) {
            float diff = w1v - (float)(k - 64) * dx;
            sEA[1][k - 64] = expf(coeff * diff * diff);
        }
    }
    __syncthreads();
    float a0 = B1i[k], a1 = a0;
    for (int g = 0; g < NG; ++g) {
        float wv = W1i[g * HID + k];
        a0 = fmaf(sEA[0][g], wv, a0);
        a1 = fmaf(sEA[1][g], wv, a1);
    }
    sT1[0][k] = ssp(a0);
    sT1[1][k] = ssp(a1);
    __syncthreads();
    float b0 = B2i[k], b1v = b0;
    for (int j = 0; j < HID; ++j) {
        float wv = W2i[j * HID + k];
        b0  = fmaf(sT1[0][j], wv, b0);
        b1v = fmaf(sT1[1][j], wv, b1v);
    }
    size_t base = ((size_t)it * TPTS + pt) * 256;
    int pair = k >> 1, within = k & 1;
    ti[base + pair * 4 + within]     = __float2half(b0);
    ti[base + pair * 4 + within + 2] = __float2half(b1v - b0);
}

// ---------------- CSR build: histogram of dst ----------------
__global__ __launch_bounds__(256) void k_hist(const int* __restrict__ ei,
                                              int* __restrict__ deg)
{
    int e = blockIdx.x * 256 + threadIdx.x;
    if (e >= NEDGES) return;
    atomicAdd(&deg[ei[NEDGES + e]], 1);
}

// ---------------- CSR build: exclusive scan, chunk-per-thread ----------------
#define SCAN_T 1024
#define CHUNK  49
__global__ __launch_bounds__(SCAN_T) void k_scan(const int* __restrict__ deg,
                                                 int* __restrict__ rowptr,
                                                 int* __restrict__ cursor)
{
    int tid = threadIdx.x;
    int base = tid * CHUNK;
    int vals[CHUNK];
    int local = 0;
    #pragma unroll
    for (int i = 0; i < CHUNK; ++i) {
        int idx = base + i;
        int v = (idx < NNODES) ? deg[idx] : 0;
        vals[i] = local;
        local += v;
    }
    int lane = tid & 63, wid = tid >> 6;
    int x = local;
    #pragma unroll
    for (int off = 1; off < 64; off <<= 1) {
        int y = __shfl_up(x, off);
        if (lane >= off) x += y;
    }
    __shared__ int wsum[16];
    __shared__ int woff[17];
    if (lane == 63) wsum[wid] = x;
    __syncthreads();
    if (tid == 0) {
        int acc = 0;
        #pragma unroll
        for (int i = 0; i < 16; ++i) { woff[i] = acc; acc += wsum[i]; }
        woff[16] = acc;
    }
    __syncthreads();
    int threadExcl = woff[wid] + x - local;
    #pragma unroll
    for (int i = 0; i < CHUNK; ++i) {
        int idx = base + i;
        if (idx < NNODES) {
            int p = threadExcl + vals[i];
            rowptr[idx] = p;
            cursor[idx] = p;
        }
    }
    if (tid == SCAN_T - 1) rowptr[NNODES] = woff[16];
}

// ---------------- CSR build: scatter rich edge records, sorted by dst ----------------
__global__ __launch_bounds__(256) void k_scatter(const int* __restrict__ ei,
                                                 const float* __restrict__ pos,
                                                 const float* __restrict__ shift,
                                                 int* __restrict__ cursor,
                                                 uint4* __restrict__ rec)
{
    int e = blockIdx.x * 256 + threadIdx.x;
    if (e >= NEDGES) return;
    int s = ei[e], d = ei[NEDGES + e];
    float rx = pos[3*s+0] - (pos[3*d+0] + shift[3*e+0]);
    float ry = pos[3*s+1] - (pos[3*d+1] + shift[3*e+1]);
    float rz = pos[3*s+2] - (pos[3*d+2] + shift[3*e+2]);
    float w = sqrtf(rx*rx + ry*ry + rz*rz);
    const float SCALE = (float)(TPTS - 1) / WMAX;
    float t = fminf(w * SCALE, (float)(TPTS - 1));
    int i0 = (int)t; if (i0 > TPTS - 2) i0 = TPTS - 2;
    float fr = t - (float)i0;
    float C = 0.5f * (cosf(w * (PI_F / 8.0f)) + 1.0f);
    __half2 fr2 = __float2half2_rn(fr);
    __half2 c2  = __float2half2_rn(C);
    int slot = atomicAdd(&cursor[d], 1);
    rec[slot] = make_uint4((unsigned)(s * 256), (unsigned)(i0 * 512),
                           *(unsigned*)&fr2, *(unsigned*)&c2);
}

// ---------------- gather: packed fp16 math, scalar-base addressing ----------------
__device__ __forceinline__ void edge_contrib(uint4 rv,
                                             const char* __restrict__ hfLane,
                                             const char* __restrict__ tbLane,
                                             float& ax, float& ay)
{
    int srcB = __builtin_amdgcn_readfirstlane((int)rv.x);
    int tblO = __builtin_amdgcn_readfirstlane((int)rv.y);
    int fru  = __builtin_amdgcn_readfirstlane((int)rv.z);
    int cu   = __builtin_amdgcn_readfirstlane((int)rv.w);
    __half2 fr2 = *reinterpret_cast<__half2*>(&fru);
    __half2 c2  = *reinterpret_cast<__half2*>(&cu);
    uint2 tv = *reinterpret_cast<const uint2*>(tbLane + tblO);
    __half2 hv = *reinterpret_cast<const __half2*>(hfLane + srcB);
    __half2 vals = *reinterpret_cast<__half2*>(&tv.x);
    __half2 dels = *reinterpret_cast<__half2*>(&tv.y);
    __half2 f2 = __hfma2(fr2, dels, vals);
    __half2 ch = __hmul2(c2, hv);
    ax = fmaf(__low2float(f2),  __low2float(ch),  ax);
    ay = fmaf(__high2float(f2), __high2float(ch), ay);
}

__global__ __launch_bounds__(256) void k_gather(const uint4* __restrict__ rec,
                                                const int* __restrict__ rowptr,
                                                const __half* __restrict__ hfH,
                                                const __half* __restrict__ tableH,
                                                __half2* __restrict__ aggH)
{
    int node = blockIdx.x * 4 + (threadIdx.x >> 6);
    int lane = threadIdx.x & 63;
    const char* hfLane = (const char*)hfH + lane * 4;
    const char* tbLane = (const char*)tableH + lane * 8;
    int beg = rowptr[node], end = rowptr[node + 1];
    float ax0 = 0.f, ay0 = 0.f, ax1 = 0.f, ay1 = 0.f;
    int k = beg;
    for (; k + 4 <= end; k += 4) {
        uint4 r0 = rec[k], r1 = rec[k+1], r2 = rec[k+2], r3 = rec[k+3];
        edge_contrib(r0, hfLane, tbLane, ax0, ay0);
        edge_contrib(r1, hfLane, tbLane, ax1, ay1);
        edge_contrib(r2, hfLane, tbLane, ax0, ay0);
        edge_contrib(r3, hfLane, tbLane, ax1, ay1);
    }
    for (; k < end; ++k) edge_contrib(rec[k], hfLane, tbLane, ax0, ay0);
    aggH[(size_t)node * 64 + lane] = __floats2half2_rn(ax0 + ax1, ay0 + ay1);
}

// ---------------- MFMA GEMM: 16 rows/block, 4 waves split 8 col-tiles ----------------
__global__ __launch_bounds__(256) void k_ngemm_mfma(const _Float16* __restrict__ hH,
                                                    const _Float16* __restrict__ Wt,
                                                    _Float16* __restrict__ outH)
{
    int tid = threadIdx.x;
    int wave = tid >> 6, l = tid & 63;
    int lr = l & 15, lg = l >> 4;
    int r0 = blockIdx.x * 16;                 // 50000/16 = 3125 exact
    f32x4 acc[2];
    acc[0] = (f32x4){0.f, 0.f, 0.f, 0.f};
    acc[1] = (f32x4){0.f, 0.f, 0.f, 0.f};
    const _Float16* aRow = hH + (size_t)(r0 + lr) * HID;
    #pragma unroll
    for (int kk = 0; kk < 8; ++kk) {
        half4 a = *(const half4*)(aRow + kk * 16 + lg * 4);
        #pragma unroll
        for (int c = 0; c < 2; ++c) {
            int ct = wave * 2 + c;
            half4 b = *(const half4*)(Wt + (size_t)(ct * 16 + lr) * HID + kk * 16 + lg * 4);
            acc[c] = __builtin_amdgcn_mfma_f32_16x16x16f16(a, b, acc[c], 0, 0, 0);
        }
    }
    #pragma unroll
    for (int c = 0; c < 2; ++c) {
        int col = (wave * 2 + c) * 16 + lr;
        #pragma unroll
        for (int r = 0; r < 4; ++r)
            outH[(size_t)(r0 + lg * 4 + r) * HID + col] = (_Float16)acc[c][r];
    }
}

// ---------------- MFMA fused update: 16 rows/block, 4 waves, 2 phases, 1 barrier ----------------
__global__ __launch_bounds__(256) void k_update_mfma(const _Float16* __restrict__ aggH,
                                                     const _Float16* __restrict__ W2t,
                                                     const float* __restrict__ B2,
                                                     const _Float16* __restrict__ Lt,
                                                     const float* __restrict__ LB,
                                                     float* __restrict__ h,
                                                     _Float16* __restrict__ hH)
{
    __shared__ _Float16 sT[16 * 128];          // 4 KB, XOR-swizzled
    int tid = threadIdx.x;
    int wave = tid >> 6, l = tid & 63;
    int lr = l & 15, lg = l >> 4;
    int r0 = blockIdx.x * 16;

    f32x4 acc[2];
    acc[0] = (f32x4){0.f, 0.f, 0.f, 0.f};
    acc[1] = (f32x4){0.f, 0.f, 0.f, 0.f};
    const _Float16* aRow = aggH + (size_t)(r0 + lr) * HID;
    #pragma unroll
    for (int kk = 0; kk < 8; ++kk) {
        half4 a = *(const half4*)(aRow + kk * 16 + lg * 4);
        #pragma unroll
        for (int c = 0; c < 2; ++c) {
            int ct = wave * 2 + c;
            half4 b = *(const half4*)(W2t + (size_t)(ct * 16 + lr) * HID + kk * 16 + lg * 4);
            acc[c] = __builtin_amdgcn_mfma_f32_16x16x16f16(a, b, acc[c], 0, 0, 0);
        }
    }
    // ssp + bias -> swizzled LDS fp16 (each wave writes its own 32 cols)
    #pragma unroll
    for (int c = 0; c < 2; ++c) {
        int col = (wave * 2 + c) * 16 + lr;
        float bias = B2[col];
        #pragma unroll
        for (int r = 0; r < 4; ++r) {
            int rl = lg * 4 + r;
            float v = ssp(acc[c][r] + bias);
            int byte = rl * 256 + col * 2;
            byte ^= (rl & 7) << 4;
            *(_Float16*)((char*)sT + byte) = (_Float16)v;
        }
    }
    __syncthreads();
    f32x4 acc2[2];
    acc2[0] = (f32x4){0.f, 0.f, 0.f, 0.f};
    acc2[1] = (f32x4){0.f, 0.f, 0.f, 0.f};
    #pragma unroll
    for (int kk = 0; kk < 8; ++kk) {
        int byte = lr * 256 + (kk * 16 + lg * 4) * 2;
        byte ^= (lr & 7) << 4;
        half4 a = *(const half4*)((char*)sT + byte);
        #pragma unroll
        for (int c = 0; c < 2; ++c) {
            int ct = wave * 2 + c;
            half4 b = *(const half4*)(Lt + (size_t)(ct * 16 + lr) * HID + kk * 16 + lg * 4);
            acc2[c] = __builtin_amdgcn_mfma_f32_16x16x16f16(a, b, acc2[c], 0, 0, 0);
        }
    }
    #pragma unroll
    for (int c = 0; c < 2; ++c) {
        int col = (wave * 2 + c) * 16 + lr;
        float lb = LB[col];
        #pragma unroll
        for (int r = 0; r < 4; ++r) {
            int row = r0 + lg * 4 + r;
            float hv = h[(size_t)row * HID + col] + acc2[c][r] + lb;
            h[(size_t)row * HID + col] = hv;
            hH[(size_t)row * HID + col] = (_Float16)hv;
        }
    }
}

// ---------------- head: 128-row tile, fused ssp+dot+atomic ----------------
__global__ __launch_bounds__(512) void k_head(const float* __restrict__ h,
                                              const float* __restrict__ w1,
                                              const float* __restrict__ b1,
                                              const float* __restrict__ w2,
                                              const float* __restrict__ b2,
                                              const int* __restrict__ batch,
                                              float* __restrict__ sums_pad)
{
    __shared__ float sA[128 * 132];
    int r0 = blockIdx.x * 128;
    int tid = threadIdx.x;
    for (int idx = tid; idx < 128 * 32; idx += 512) {
        int r = idx >> 5, c4 = idx & 31;
        int row = r0 + r;
        float4 v = make_float4(0.f, 0.f, 0.f, 0.f);
        if (row < NNODES) v = *(const float4*)(h + (size_t)row * HID + c4 * 4);
        *(float4*)(&sA[r * 132 + c4 * 4]) = v;
    }
    __syncthreads();
    int tx = tid & 7, ty = tid >> 3;
    int cc = tx * 8, ee = ty * 2;
    float acc[2][8];
    {
        float4 b0 = *(const float4*)(b1 + cc);
        float4 bb = *(const float4*)(b1 + cc + 4);
        #pragma unroll
        for (int e = 0; e < 2; ++e) {
            acc[e][0]=b0.x; acc[e][1]=b0.y; acc[e][2]=b0.z; acc[e][3]=b0.w;
            acc[e][4]=bb.x; acc[e][5]=bb.y; acc[e][6]=bb.z; acc[e][7]=bb.w;
        }
    }
    #pragma unroll 4
    for (int j = 0; j < HID; ++j) {
        float a0 = sA[(ee + 0) * 132 + j];
        float a1 = sA[(ee + 1) * 132 + j];
        float4 w0 = *(const float4*)(w1 + (size_t)j * 64 + cc);
        float4 wv1 = *(const float4*)(w1 + (size_t)j * 64 + cc + 4);
        float wv[8] = {w0.x,w0.y,w0.z,w0.w,wv1.x,wv1.y,wv1.z,wv1.w};
        #pragma unroll
        for (int c = 0; c < 8; ++c) {
            acc[0][c] = fmaf(a0, wv[c], acc[0][c]);
            acc[1][c] = fmaf(a1, wv[c], acc[1][c]);
        }
    }
    float4 w2a = *(const float4*)(w2 + cc);
    float4 w2b = *(const float4*)(w2 + cc + 4);
    float w2v[8] = {w2a.x,w2a.y,w2a.z,w2a.w,w2b.x,w2b.y,w2b.z,w2b.w};
    float bias2 = b2[0];
    #pragma unroll
    for (int e = 0; e < 2; ++e) {
        float part = 0.f;
        #pragma unroll
        for (int c = 0; c < 8; ++c) part = fmaf(ssp(acc[e][c]), w2v[c], part);
        part += __shfl_down(part, 4, 8);
        part += __shfl_down(part, 2, 8);
        part += __shfl_down(part, 1, 8);
        if (tx == 0) {
            int row = r0 + ee + e;
            if (row < NNODES) {
                int b = batch[row];
                atomicAdd(&sums_pad[b * 16], part + bias2);
            }
        }
    }
}

// ---------------- final: counts via binary search on sorted batch ----------------
__global__ void k_final(const float* __restrict__ sums_pad,
                        const int* __restrict__ batch,
                        float* __restrict__ out)
{
    int g = threadIdx.x;
    if (g >= NGRAPHS) return;
    int lo = 0, hi = NNODES;
    while (lo < hi) { int mid = (lo + hi) >> 1; if (batch[mid] < g) lo = mid + 1; else hi = mid; }
    int a = lo;
    lo = 0; hi = NNODES;
    while (lo < hi) { int mid = (lo + hi) >> 1; if (batch[mid] < g + 1) lo = mid + 1; else hi = mid; }
    float cnt = (float)(lo - a);
    out[g] = sums_pad[g * 16] / fmaxf(cnt, 1.0f);
}

extern "C" void kernel_launch(void* const* d_in, const int* in_sizes, int n_in,
                              void* d_out, int out_size, void* d_ws, size_t ws_size,
                              hipStream_t stream)
{
    const float* pos     = (const float*)d_in[0];
    const float* shift   = (const float*)d_in[1];
    const float* emb     = (const float*)d_in[2];
    const float* mlp_w1  = (const float*)d_in[3];
    const float* mlp_b1  = (const float*)d_in[4];
    const float* mlp_w2  = (const float*)d_in[5];
    const float* mlp_b2  = (const float*)d_in[6];
    const float* cf_w1   = (const float*)d_in[7];
    const float* cf_w2   = (const float*)d_in[8];
    const float* cf_b2   = (const float*)d_in[9];
    const float* lin_w   = (const float*)d_in[10];
    const float* lin_b   = (const float*)d_in[11];
    const float* head_w1 = (const float*)d_in[12];
    const float* head_b1 = (const float*)d_in[13];
    const float* head_w2 = (const float*)d_in[14];
    const float* head_b2 = (const float*)d_in[15];
    const int*   z       = (const int*)d_in[16];
    const int*   ei      = (const int*)d_in[17];
    const int*   batch   = (const int*)d_in[18];
    float* out = (float*)d_out;

    float* ws = (float*)d_ws;
    size_t off = 0;
    float*    h       = ws + off; off += (size_t)NNODES * HID;
    _Float16* hH      = (_Float16*)(ws + off); off += (size_t)(NNODES + 64) * HID / 2;
    _Float16* hfH     = (_Float16*)(ws + off); off += (size_t)(NNODES + 64) * HID / 2;
    _Float16* aggH    = (_Float16*)(ws + off); off += (size_t)(NNODES + 64) * HID / 2;
    __half*   tableH  = (__half*)(ws + off); off += (size_t)3 * TPTS * 256 / 2;
    _Float16* w1t     = (_Float16*)(ws + off); off += (size_t)3 * HID * HID / 2;
    _Float16* w2t     = (_Float16*)(ws + off); off += (size_t)3 * HID * HID / 2;
    _Float16* lwt     = (_Float16*)(ws + off); off += (size_t)3 * HID * HID / 2;
    uint4*    rec     = (uint4*)(ws + off); off += (size_t)4 * NEDGES;
    int*      rowptr  = (int*)(ws + off); off += NNODES + 1;
    int*      deg     = (int*)(ws + off); off += NNODES;
    int*      cursor  = (int*)(ws + off); off += NNODES;
    float*    sums_pad= ws + off; off += NGRAPHS * 16;

    hipMemsetAsync(deg, 0, NNODES * sizeof(int), stream);
    hipMemsetAsync(sums_pad, 0, NGRAPHS * 16 * sizeof(float), stream);

    k_hist<<<(NEDGES + 255) / 256, 256, 0, stream>>>(ei, deg);
    k_scan<<<1, SCAN_T, 0, stream>>>(deg, rowptr, cursor);
    k_scatter<<<(NEDGES + 255) / 256, 256, 0, stream>>>(ei, pos, shift, cursor, rec);

    k_init_h<<<NNODES * HID / 256, 256, 0, stream>>>(emb, z, h, hH);
    k_table<<<3 * TPTS, 128, 0, stream>>>(mlp_w1, mlp_b1, mlp_w2, mlp_b2, tableH);
    k_wt<<<3 * 128, 128, 0, stream>>>(cf_w1, w1t);
    k_wt<<<3 * 128, 128, 0, stream>>>(cf_w2, w2t);
    k_wt<<<3 * 128, 128, 0, stream>>>(lin_w, lwt);

    int gblk = NNODES / 16;     // 3125
    for (int i = 0; i < NITER; ++i) {
        k_ngemm_mfma<<<gblk, 256, 0, stream>>>(hH, w1t + (size_t)i * HID * HID, hfH);
        k_gather<<<NNODES / 4, 256, 0, stream>>>(rec, rowptr, (const __half*)hfH,
                                                 tableH + (size_t)i * TPTS * 256,
                                                 (__half2*)aggH);
        k_update_mfma<<<gblk, 256, 0, stream>>>(aggH, w2t + (size_t)i * HID * HID,
                                                cf_b2 + (size_t)i * HID,
                                                lwt + (size_t)i * HID * HID,
                                                lin_b + (size_t)i * HID, h, hH);
    }
    k_head<<<(NNODES + 127) / 128, 512, 0, stream>>>(h, head_w1, head_b1, head_w2, head_b2, batch, sums_pad);
    k_final<<<1, 128, 0, stream>>>(sums_pad, batch, out);
}

// Round 9
// 1016.010 us; speedup vs baseline: 1.1514x; 1.0834x over previous
//
#include <hip/hip_runtime.h>
#include <hip/hip_fp16.h>
#include <math.h>

#define NNODES  50000
#define NEDGES  1600000
#define NGRAPHS 128
#define HID     128
#define NG      50
#define NITER   3
#define TPTS    2048
#define WMAX    12.0f
#define PI_F    3.14159265358979323846f

typedef __attribute__((ext_vector_type(4))) _Float16 half4;
typedef __attribute__((ext_vector_type(4))) float   f32x4;

__device__ __forceinline__ float ssp(float x) {
    float sp = fmaxf(x, 0.0f) + log1pf(expf(-fabsf(x)));
    return sp - 0.69314718055994530942f;
}

// ---------------- h = emb[z] (fp32 master + fp16 shadow) ----------------
__global__ __launch_bounds__(256) void k_init_h(const float* __restrict__ emb,
                                                const int* __restrict__ z,
                                                float* __restrict__ h,
                                                _Float16* __restrict__ hH)
{
    int idx = blockIdx.x * 256 + threadIdx.x;
    int n = idx >> 7, c = idx & 127;
    float v = emb[(z[n] << 7) + c];
    h[idx] = v;
    hH[idx] = (_Float16)v;
}

// ---------------- weight transpose+cast: out[it][c][j] = in[it][j][c] fp16 ----------------
__global__ __launch_bounds__(128) void k_wt(const float* __restrict__ in,
                                            _Float16* __restrict__ out)
{
    int it = blockIdx.x >> 7, c = blockIdx.x & 127, j = threadIdx.x;
    out[(size_t)it * 16384 + c * 128 + j] = (_Float16)in[(size_t)it * 16384 + j * 128 + c];
}

// ---------------- LUT build, fused delta: ti layout (v0,v1,d0,d1) per lane-pair ----------------
__global__ __launch_bounds__(128) void k_table(const float* __restrict__ W1,
                                               const float* __restrict__ B1,
                                               const float* __restrict__ W2,
                                               const float* __restrict__ B2,
                                               __half* __restrict__ ti)
{
    int it = blockIdx.x / TPTS;
    int pt = blockIdx.x - it * TPTS;
    const float* W1i = W1 + (size_t)it * NG * HID;
    const float* B1i = B1 + (size_t)it * HID;
    const float* W2i = W2 + (size_t)it * HID * HID;
    const float* B2i = B2 + (size_t)it * HID;

    const float step = WMAX / (float)(TPTS - 1);
    float w0 = pt * step;
    int ptn = (pt < TPTS - 1) ? pt + 1 : pt;
    float w1v = ptn * step;

    __shared__ float sEA[2][NG];
    __shared__ float sT1[2][HID];
    int k = threadIdx.x;
    {
        float dx = 8.0f / 49.0f;
        float coeff = -0.5f / (dx * dx);
        if (k < NG) {
            float diff = w0 - (float)k * dx;
            sEA[0][k] = expf(coeff * diff * diff);
        } else if (k >= 64 && k < 64 + NG) {
            float diff = w1v - (float)(k - 64) * dx;
            sEA[1][k - 64] = expf(coeff * diff * diff);
        }
    }
    __syncthreads();
    float a0 = B1i[k], a1 = a0;
    for (int g = 0; g < NG; ++g) {
        float wv = W1i[g * HID + k];
        a0 = fmaf(sEA[0][g], wv, a0);
        a1 = fmaf(sEA[1][g], wv, a1);
    }
    sT1[0][k] = ssp(a0);
    sT1[1][k] = ssp(a1);
    __syncthreads();
    float b0 = B2i[k], b1v = b0;
    for (int j = 0; j < HID; ++j) {
        float wv = W2i[j * HID + k];
        b0  = fmaf(sT1[0][j], wv, b0);
        b1v = fmaf(sT1[1][j], wv, b1v);
    }
    size_t base = ((size_t)it * TPTS + pt) * 256;
    int pair = k >> 1, within = k & 1;
    ti[base + pair * 4 + within]     = __float2half(b0);
    ti[base + pair * 4 + within + 2] = __float2half(b1v - b0);
}

// ---------------- CSR build: histogram of dst ----------------
__global__ __launch_bounds__(256) void k_hist(const int* __restrict__ ei,
                                              int* __restrict__ deg)
{
    int e = blockIdx.x * 256 + threadIdx.x;
    if (e >= NEDGES) return;
    atomicAdd(&deg[ei[NEDGES + e]], 1);
}

// ---------------- CSR build: exclusive scan, chunk-per-thread ----------------
#define SCAN_T 1024
#define CHUNK  49
__global__ __launch_bounds__(SCAN_T) void k_scan(const int* __restrict__ deg,
                                                 int* __restrict__ rowptr,
                                                 int* __restrict__ cursor)
{
    int tid = threadIdx.x;
    int base = tid * CHUNK;
    int vals[CHUNK];
    int local = 0;
    #pragma unroll
    for (int i = 0; i < CHUNK; ++i) {
        int idx = base + i;
        int v = (idx < NNODES) ? deg[idx] : 0;
        vals[i] = local;
        local += v;
    }
    int lane = tid & 63, wid = tid >> 6;
    int x = local;
    #pragma unroll
    for (int off = 1; off < 64; off <<= 1) {
        int y = __shfl_up(x, off);
        if (lane >= off) x += y;
    }
    __shared__ int wsum[16];
    __shared__ int woff[17];
    if (lane == 63) wsum[wid] = x;
    __syncthreads();
    if (tid == 0) {
        int acc = 0;
        #pragma unroll
        for (int i = 0; i < 16; ++i) { woff[i] = acc; acc += wsum[i]; }
        woff[16] = acc;
    }
    __syncthreads();
    int threadExcl = woff[wid] + x - local;
    #pragma unroll
    for (int i = 0; i < CHUNK; ++i) {
        int idx = base + i;
        if (idx < NNODES) {
            int p = threadExcl + vals[i];
            rowptr[idx] = p;
            cursor[idx] = p;
        }
    }
    if (tid == SCAN_T - 1) rowptr[NNODES] = woff[16];
}

// ---------------- CSR build: scatter packed edge records, sorted by dst ----------------
// rec.x = src | (i0 << 17)  (src < 2^17, i0 < 2^11);  rec.y = half2(fr, C)
__global__ __launch_bounds__(256) void k_scatter(const int* __restrict__ ei,
                                                 const float* __restrict__ pos,
                                                 const float* __restrict__ shift,
                                                 int* __restrict__ cursor,
                                                 uint2* __restrict__ rec)
{
    int e = blockIdx.x * 256 + threadIdx.x;
    if (e >= NEDGES) return;
    int s = ei[e], d = ei[NEDGES + e];
    float rx = pos[3*s+0] - (pos[3*d+0] + shift[3*e+0]);
    float ry = pos[3*s+1] - (pos[3*d+1] + shift[3*e+1]);
    float rz = pos[3*s+2] - (pos[3*d+2] + shift[3*e+2]);
    float w = sqrtf(rx*rx + ry*ry + rz*rz);
    const float SCALE = (float)(TPTS - 1) / WMAX;
    float t = fminf(w * SCALE, (float)(TPTS - 1));
    int i0 = (int)t; if (i0 > TPTS - 2) i0 = TPTS - 2;
    float fr = t - (float)i0;
    float C = 0.5f * (cosf(w * (PI_F / 8.0f)) + 1.0f);
    __half2 frc = __halves2half2(__float2half(fr), __float2half(C));
    int slot = atomicAdd(&cursor[d], 1);
    rec[slot] = make_uint2((unsigned)s | ((unsigned)i0 << 17), *(unsigned*)&frc);
}

// ---------------- gather: per-lane decode, packed fp16 math ----------------
__device__ __forceinline__ void edge_contrib(uint2 rv, int lane,
                                             const char* __restrict__ hfBase,
                                             const char* __restrict__ tbBase,
                                             float& ax, float& ay)
{
    unsigned sB = (rv.x & 0x1FFFFu) << 8;          // src * 256 bytes
    unsigned tB = (rv.x >> 17) << 9;               // i0 * 512 bytes
    __half2 frc = *reinterpret_cast<__half2*>(&rv.y);
    __half2 fr2 = __half2half2(__low2half(frc));   // splat fr
    __half2 c2  = __half2half2(__high2half(frc));  // splat C
    uint2 tv = *reinterpret_cast<const uint2*>(tbBase + tB + lane * 8);
    unsigned hu = *reinterpret_cast<const unsigned*>(hfBase + sB + lane * 4);
    __half2 hv   = *reinterpret_cast<__half2*>(&hu);
    __half2 vals = *reinterpret_cast<__half2*>(&tv.x);
    __half2 dels = *reinterpret_cast<__half2*>(&tv.y);
    __half2 f2 = __hfma2(fr2, dels, vals);         // v_pk_fma_f16 lerp
    __half2 ch = __hmul2(c2, hv);                  // v_pk_mul_f16
    ax = fmaf(__low2float(f2),  __low2float(ch),  ax);   // v_fma_mix
    ay = fmaf(__high2float(f2), __high2float(ch), ay);
}

__global__ __launch_bounds__(256) void k_gather(const uint2* __restrict__ rec,
                                                const int* __restrict__ rowptr,
                                                const __half* __restrict__ hfH,
                                                const __half* __restrict__ tableH,
                                                __half2* __restrict__ aggH)
{
    int node = blockIdx.x * 4 + (threadIdx.x >> 6);
    int lane = threadIdx.x & 63;
    const char* hfBase = (const char*)hfH;
    const char* tbBase = (const char*)tableH;
    int beg = rowptr[node], end = rowptr[node + 1];
    float ax0 = 0.f, ay0 = 0.f, ax1 = 0.f, ay1 = 0.f;
    int k = beg;
    for (; k + 4 <= end; k += 4) {
        uint2 r0 = rec[k], r1 = rec[k+1], r2 = rec[k+2], r3 = rec[k+3];
        edge_contrib(r0, lane, hfBase, tbBase, ax0, ay0);
        edge_contrib(r1, lane, hfBase, tbBase, ax1, ay1);
        edge_contrib(r2, lane, hfBase, tbBase, ax0, ay0);
        edge_contrib(r3, lane, hfBase, tbBase, ax1, ay1);
    }
    for (; k < end; ++k) edge_contrib(rec[k], lane, hfBase, tbBase, ax0, ay0);
    aggH[(size_t)node * 64 + lane] = __floats2half2_rn(ax0 + ax1, ay0 + ay1);
}

// ---------------- MFMA GEMM: 16 rows/block, 4 waves split 8 col-tiles ----------------
__global__ __launch_bounds__(256) void k_ngemm_mfma(const _Float16* __restrict__ hH,
                                                    const _Float16* __restrict__ Wt,
                                                    _Float16* __restrict__ outH)
{
    int tid = threadIdx.x;
    int wave = tid >> 6, l = tid & 63;
    int lr = l & 15, lg = l >> 4;
    int r0 = blockIdx.x * 16;                 // 50000/16 = 3125 exact
    f32x4 acc[2];
    acc[0] = (f32x4){0.f, 0.f, 0.f, 0.f};
    acc[1] = (f32x4){0.f, 0.f, 0.f, 0.f};
    const _Float16* aRow = hH + (size_t)(r0 + lr) * HID;
    #pragma unroll
    for (int kk = 0; kk < 8; ++kk) {
        half4 a = *(const half4*)(aRow + kk * 16 + lg * 4);
        #pragma unroll
        for (int c = 0; c < 2; ++c) {
            int ct = wave * 2 + c;
            half4 b = *(const half4*)(Wt + (size_t)(ct * 16 + lr) * HID + kk * 16 + lg * 4);
            acc[c] = __builtin_amdgcn_mfma_f32_16x16x16f16(a, b, acc[c], 0, 0, 0);
        }
    }
    #pragma unroll
    for (int c = 0; c < 2; ++c) {
        int col = (wave * 2 + c) * 16 + lr;
        #pragma unroll
        for (int r = 0; r < 4; ++r)
            outH[(size_t)(r0 + lg * 4 + r) * HID + col] = (_Float16)acc[c][r];
    }
}

// ---------------- MFMA fused update: 16 rows/block, 4 waves, 2 phases, 1 barrier ----------------
__global__ __launch_bounds__(256) void k_update_mfma(const _Float16* __restrict__ aggH,
                                                     const _Float16* __restrict__ W2t,
                                                     const float* __restrict__ B2,
                                                     const _Float16* __restrict__ Lt,
                                                     const float* __restrict__ LB,
                                                     float* __restrict__ h,
                                                     _Float16* __restrict__ hH)
{
    __shared__ _Float16 sT[16 * 128];          // 4 KB, XOR-swizzled
    int tid = threadIdx.x;
    int wave = tid >> 6, l = tid & 63;
    int lr = l & 15, lg = l >> 4;
    int r0 = blockIdx.x * 16;

    f32x4 acc[2];
    acc[0] = (f32x4){0.f, 0.f, 0.f, 0.f};
    acc[1] = (f32x4){0.f, 0.f, 0.f, 0.f};
    const _Float16* aRow = aggH + (size_t)(r0 + lr) * HID;
    #pragma unroll
    for (int kk = 0; kk < 8; ++kk) {
        half4 a = *(const half4*)(aRow + kk * 16 + lg * 4);
        #pragma unroll
        for (int c = 0; c < 2; ++c) {
            int ct = wave * 2 + c;
            half4 b = *(const half4*)(W2t + (size_t)(ct * 16 + lr) * HID + kk * 16 + lg * 4);
            acc[c] = __builtin_amdgcn_mfma_f32_16x16x16f16(a, b, acc[c], 0, 0, 0);
        }
    }
    #pragma unroll
    for (int c = 0; c < 2; ++c) {
        int col = (wave * 2 + c) * 16 + lr;
        float bias = B2[col];
        #pragma unroll
        for (int r = 0; r < 4; ++r) {
            int rl = lg * 4 + r;
            float v = ssp(acc[c][r] + bias);
            int byte = rl * 256 + col * 2;
            byte ^= (rl & 7) << 4;
            *(_Float16*)((char*)sT + byte) = (_Float16)v;
        }
    }
    __syncthreads();
    f32x4 acc2[2];
    acc2[0] = (f32x4){0.f, 0.f, 0.f, 0.f};
    acc2[1] = (f32x4){0.f, 0.f, 0.f, 0.f};
    #pragma unroll
    for (int kk = 0; kk < 8; ++kk) {
        int byte = lr * 256 + (kk * 16 + lg * 4) * 2;
        byte ^= (lr & 7) << 4;
        half4 a = *(const half4*)((char*)sT + byte);
        #pragma unroll
        for (int c = 0; c < 2; ++c) {
            int ct = wave * 2 + c;
            half4 b = *(const half4*)(Lt + (size_t)(ct * 16 + lr) * HID + kk * 16 + lg * 4);
            acc2[c] = __builtin_amdgcn_mfma_f32_16x16x16f16(a, b, acc2[c], 0, 0, 0);
        }
    }
    #pragma unroll
    for (int c = 0; c < 2; ++c) {
        int col = (wave * 2 + c) * 16 + lr;
        float lb = LB[col];
        #pragma unroll
        for (int r = 0; r < 4; ++r) {
            int row = r0 + lg * 4 + r;
            float hv = h[(size_t)row * HID + col] + acc2[c][r] + lb;
            h[(size_t)row * HID + col] = hv;
            hH[(size_t)row * HID + col] = (_Float16)hv;
        }
    }
}

// ---------------- head: 128-row tile, fused ssp+dot+atomic ----------------
__global__ __launch_bounds__(512) void k_head(const float* __restrict__ h,
                                              const float* __restrict__ w1,
                                              const float* __restrict__ b1,
                                              const float* __restrict__ w2,
                                              const float* __restrict__ b2,
                                              const int* __restrict__ batch,
                                              float* __restrict__ sums_pad)
{
    __shared__ float sA[128 * 132];
    int r0 = blockIdx.x * 128;
    int tid = threadIdx.x;
    for (int idx = tid; idx < 128 * 32; idx += 512) {
        int r = idx >> 5, c4 = idx & 31;
        int row = r0 + r;
        float4 v = make_float4(0.f, 0.f, 0.f, 0.f);
        if (row < NNODES) v = *(const float4*)(h + (size_t)row * HID + c4 * 4);
        *(float4*)(&sA[r * 132 + c4 * 4]) = v;
    }
    __syncthreads();
    int tx = tid & 7, ty = tid >> 3;
    int cc = tx * 8, ee = ty * 2;
    float acc[2][8];
    {
        float4 b0 = *(const float4*)(b1 + cc);
        float4 bb = *(const float4*)(b1 + cc + 4);
        #pragma unroll
        for (int e = 0; e < 2; ++e) {
            acc[e][0]=b0.x; acc[e][1]=b0.y; acc[e][2]=b0.z; acc[e][3]=b0.w;
            acc[e][4]=bb.x; acc[e][5]=bb.y; acc[e][6]=bb.z; acc[e][7]=bb.w;
        }
    }
    #pragma unroll 4
    for (int j = 0; j < HID; ++j) {
        float a0 = sA[(ee + 0) * 132 + j];
        float a1 = sA[(ee + 1) * 132 + j];
        float4 w0 = *(const float4*)(w1 + (size_t)j * 64 + cc);
        float4 wv1 = *(const float4*)(w1 + (size_t)j * 64 + cc + 4);
        float wv[8] = {w0.x,w0.y,w0.z,w0.w,wv1.x,wv1.y,wv1.z,wv1.w};
        #pragma unroll
        for (int c = 0; c < 8; ++c) {
            acc[0][c] = fmaf(a0, wv[c], acc[0][c]);
            acc[1][c] = fmaf(a1, wv[c], acc[1][c]);
        }
    }
    float4 w2a = *(const float4*)(w2 + cc);
    float4 w2b = *(const float4*)(w2 + cc + 4);
    float w2v[8] = {w2a.x,w2a.y,w2a.z,w2a.w,w2b.x,w2b.y,w2b.z,w2b.w};
    float bias2 = b2[0];
    #pragma unroll
    for (int e = 0; e < 2; ++e) {
        float part = 0.f;
        #pragma unroll
        for (int c = 0; c < 8; ++c) part = fmaf(ssp(acc[e][c]), w2v[c], part);
        part += __shfl_down(part, 4, 8);
        part += __shfl_down(part, 2, 8);
        part += __shfl_down(part, 1, 8);
        if (tx == 0) {
            int row = r0 + ee + e;
            if (row < NNODES) {
                int b = batch[row];
                atomicAdd(&sums_pad[b * 16], part + bias2);
            }
        }
    }
}

// ---------------- final: counts via binary search on sorted batch ----------------
__global__ void k_final(const float* __restrict__ sums_pad,
                        const int* __restrict__ batch,
                        float* __restrict__ out)
{
    int g = threadIdx.x;
    if (g >= NGRAPHS) return;
    int lo = 0, hi = NNODES;
    while (lo < hi) { int mid = (lo + hi) >> 1; if (batch[mid] < g) lo = mid + 1; else hi = mid; }
    int a = lo;
    lo = 0; hi = NNODES;
    while (lo < hi) { int mid = (lo + hi) >> 1; if (batch[mid] < g + 1) lo = mid + 1; else hi = mid; }
    float cnt = (float)(lo - a);
    out[g] = sums_pad[g * 16] / fmaxf(cnt, 1.0f);
}

extern "C" void kernel_launch(void* const* d_in, const int* in_sizes, int n_in,
                              void* d_out, int out_size, void* d_ws, size_t ws_size,
                              hipStream_t stream)
{
    const float* pos     = (const float*)d_in[0];
    const float* shift   = (const float*)d_in[1];
    const float* emb     = (const float*)d_in[2];
    const float* mlp_w1  = (const float*)d_in[3];
    const float* mlp_b1  = (const float*)d_in[4];
    const float* mlp_w2  = (const float*)d_in[5];
    const float* mlp_b2  = (const float*)d_in[6];
    const float* cf_w1   = (const float*)d_in[7];
    const float* cf_w2   = (const float*)d_in[8];
    const float* cf_b2   = (const float*)d_in[9];
    const float* lin_w   = (const float*)d_in[10];
    const float* lin_b   = (const float*)d_in[11];
    const float* head_w1 = (const float*)d_in[12];
    const float* head_b1 = (const float*)d_in[13];
    const float* head_w2 = (const float*)d_in[14];
    const float* head_b2 = (const float*)d_in[15];
    const int*   z       = (const int*)d_in[16];
    const int*   ei      = (const int*)d_in[17];
    const int*   batch   = (const int*)d_in[18];
    float* out = (float*)d_out;

    float* ws = (float*)d_ws;
    size_t off = 0;
    float*    h       = ws + off; off += (size_t)NNODES * HID;
    _Float16* hH      = (_Float16*)(ws + off); off += (size_t)(NNODES + 64) * HID / 2;
    _Float16* hfH     = (_Float16*)(ws + off); off += (size_t)(NNODES + 64) * HID / 2;
    _Float16* aggH    = (_Float16*)(ws + off); off += (size_t)(NNODES + 64) * HID / 2;
    __half*   tableH  = (__half*)(ws + off); off += (size_t)3 * TPTS * 256 / 2;
    _Float16* w1t     = (_Float16*)(ws + off); off += (size_t)3 * HID * HID / 2;
    _Float16* w2t     = (_Float16*)(ws + off); off += (size_t)3 * HID * HID / 2;
    _Float16* lwt     = (_Float16*)(ws + off); off += (size_t)3 * HID * HID / 2;
    uint2*    rec     = (uint2*)(ws + off); off += (size_t)2 * NEDGES;
    int*      rowptr  = (int*)(ws + off); off += NNODES + 1;
    int*      deg     = (int*)(ws + off); off += NNODES;
    int*      cursor  = (int*)(ws + off); off += NNODES;
    float*    sums_pad= ws + off; off += NGRAPHS * 16;

    hipMemsetAsync(deg, 0, NNODES * sizeof(int), stream);
    hipMemsetAsync(sums_pad, 0, NGRAPHS * 16 * sizeof(float), stream);

    k_hist<<<(NEDGES + 255) / 256, 256, 0, stream>>>(ei, deg);
    k_scan<<<1, SCAN_T, 0, stream>>>(deg, rowptr, cursor);
    k_scatter<<<(NEDGES + 255) / 256, 256, 0, stream>>>(ei, pos, shift, cursor, rec);

    k_init_h<<<NNODES * HID / 256, 256, 0, stream>>>(emb, z, h, hH);
    k_table<<<3 * TPTS, 128, 0, stream>>>(mlp_w1, mlp_b1, mlp_w2, mlp_b2, tableH);
    k_wt<<<3 * 128, 128, 0, stream>>>(cf_w1, w1t);
    k_wt<<<3 * 128, 128, 0, stream>>>(cf_w2, w2t);
    k_wt<<<3 * 128, 128, 0, stream>>>(lin_w, lwt);

    int gblk = NNODES / 16;     // 3125
    for (int i = 0; i < NITER; ++i) {
        k_ngemm_mfma<<<gblk, 256, 0, stream>>>(hH, w1t + (size_t)i * HID * HID, hfH);
        k_gather<<<NNODES / 4, 256, 0, stream>>>(rec, rowptr, (const __half*)hfH,
                                                 tableH + (size_t)i * TPTS * 256,
                                                 (__half2*)aggH);
        k_update_mfma<<<gblk, 256, 0, stream>>>(aggH, w2t + (size_t)i * HID * HID,
                                                cf_b2 + (size_t)i * HID,
                                                lwt + (size_t)i * HID * HID,
                                                lin_b + (size_t)i * HID, h, hH);
    }
    k_head<<<(NNODES + 127) / 128, 512, 0, stream>>>(h, head_w1, head_b1, head_w2, head_b2, batch, sums_pad);
    k_final<<<1, 128, 0, stream>>>(sums_pad, batch, out);
}